// Round 8
// baseline (113.610 us; speedup 1.0000x reference)
//
#include <hip/hip_runtime.h>
#include <cstdint>

#define NA_N 50000
#define NB_N 50000
#define NE_N 800000
#define DD 256

using bf8   = __attribute__((ext_vector_type(8))) short;   // 8 bf16 = 4 VGPR
using f32x4 = __attribute__((ext_vector_type(4))) float;
using u32x2 = __attribute__((ext_vector_type(2))) unsigned int;

__device__ __forceinline__ ushort f2bf(float f) {
    uint u = __float_as_uint(f);
    uint r = (u + 0x7fffu + ((u >> 16) & 1u)) >> 16;       // RNE
    return (ushort)r;
}

// ------- prep: blocks 0-15 transpose+cast W -> Wt[n][k] (bf16); rest build row_start -------
__global__ __launch_bounds__(256) void prep_k(const float* __restrict__ W,
    ushort* __restrict__ Wt, const int* __restrict__ esrc,
    int* __restrict__ row_start)
{
    if (blockIdx.x < 16) {
        __shared__ float T[64][65];
        const int bi = blockIdx.x & 3;
        const int bj = blockIdx.x >> 2;
        const int lane = threadIdx.x & 63, w = threadIdx.x >> 6;
        for (int i = w; i < 64; i += 4)
            T[i][lane] = W[(size_t)(bi * 64 + i) * DD + bj * 64 + lane];
        __syncthreads();
        for (int i = w; i < 64; i += 4)
            Wt[(size_t)(bj * 64 + i) * DD + bi * 64 + lane] = f2bf(T[lane][i]);
    } else {
        int e = (blockIdx.x - 16) * 256 + threadIdx.x;
        if (e >= NE_N) return;
        int s    = esrc[e];
        int prev = (e == 0) ? -1 : esrc[e - 1];
        for (int r = prev + 1; r <= s; r++) row_start[r] = e;
        if (e == NE_N - 1)
            for (int r = s + 1; r <= NA_N; r++) row_start[r] = NE_N;
    }
}

// ------- GEMM: emb_b[NB,256](bf16) = bf16(fb) @ W + bias ; fused s_b = emb @ a_bot -------
__global__ __launch_bounds__(256) void gemm_mfma(
    const float* __restrict__ A, const ushort* __restrict__ Wt,
    const float* __restrict__ bias, const float* __restrict__ a_bot,
    ushort* __restrict__ C, float* __restrict__ s_b)
{
    __shared__ ushort As[64 * 264];
    __shared__ float  sdot[4][64];
    const int t  = threadIdx.x;
    const int r0 = blockIdx.x * 64;

#pragma unroll
    for (int i = 0; i < 16; i++) {
        int flat = i * 256 + t;
        int row  = flat >> 6;
        int c4   = flat & 63;
        int gr   = r0 + row; if (gr >= NB_N) gr = 0;
        float4 v = ((const float4*)(A + (size_t)gr * DD))[c4];
        ushort4 b;
        b.x = f2bf(v.x); b.y = f2bf(v.y); b.z = f2bf(v.z); b.w = f2bf(v.w);
        *(ushort4*)&As[row * 264 + c4 * 4] = b;
    }
    __syncthreads();

    const int lane = t & 63;
    const int wv   = t >> 6;
    const int lr   = lane & 15;
    const int lk   = (lane >> 4) * 8;

    f32x4 acc[4][4];
#pragma unroll
    for (int m = 0; m < 4; m++)
#pragma unroll
        for (int n = 0; n < 4; n++) acc[m][n] = (f32x4){0.f, 0.f, 0.f, 0.f};

#pragma unroll
    for (int ks = 0; ks < 8; ks++) {
        const int k0 = ks * 32;
        bf8 af[4], bb[4];
#pragma unroll
        for (int m = 0; m < 4; m++)
            af[m] = *(const bf8*)&As[(m * 16 + lr) * 264 + k0 + lk];
#pragma unroll
        for (int n = 0; n < 4; n++) {
            int col = wv * 64 + n * 16 + lr;
            bb[n] = *(const bf8*)&Wt[(size_t)col * DD + k0 + lk];
        }
#pragma unroll
        for (int m = 0; m < 4; m++)
#pragma unroll
            for (int n = 0; n < 4; n++)
                acc[m][n] = __builtin_amdgcn_mfma_f32_16x16x32_bf16(
                    af[m], bb[n], acc[m][n], 0, 0, 0);
    }

    float abv[4];
#pragma unroll
    for (int n = 0; n < 4; n++) abv[n] = a_bot[wv * 64 + n * 16 + lr];

    float part[4][4];
#pragma unroll
    for (int m = 0; m < 4; m++)
#pragma unroll
        for (int r = 0; r < 4; r++) part[m][r] = 0.f;

#pragma unroll
    for (int m = 0; m < 4; m++)
#pragma unroll
        for (int n = 0; n < 4; n++) {
            int   col = wv * 64 + n * 16 + lr;
            float bv  = bias[col];
#pragma unroll
            for (int r = 0; r < 4; r++) {
                int   rowg = r0 + m * 16 + (lane >> 4) * 4 + r;
                float v    = acc[m][n][r] + bv;
                if (rowg < NB_N) C[(size_t)rowg * DD + col] = f2bf(v);
                part[m][r] = fmaf(v, abv[n], part[m][r]);
            }
        }

#pragma unroll
    for (int m = 0; m < 4; m++)
#pragma unroll
        for (int r = 0; r < 4; r++) {
#pragma unroll
            for (int off = 1; off < 16; off <<= 1)
                part[m][r] += __shfl_xor(part[m][r], off, 64);
        }
    if (lr == 0) {
#pragma unroll
        for (int m = 0; m < 4; m++)
#pragma unroll
            for (int r = 0; r < 4; r++)
                sdot[wv][m * 16 + (lane >> 4) * 4 + r] = part[m][r];
    }
    __syncthreads();
    if (t < 64) {
        int rowg = r0 + t;
        if (rowg < NB_N)
            s_b[rowg] = sdot[0][t] + sdot[1][t] + sdot[2][t] + sdot[3][t];
    }
}

// -------- edge aggregation as MFMA: block = 16 src rows; chunk = 32 edges --------
// B (32 gathered emb rows) staged to LDS via global_load_lds with pre-swizzled
// source so linear LDS writes land in [kq][c][4][16] subtiles for ds_read_b64_tr_b16.
// A (16x32 scores, bf16) built in registers via shuffles. Double-buffered LDS,
// counted vmcnt(7), raw barriers; ones-column MFMA produces row sums.
__global__ __launch_bounds__(256) void edge_mfma(
    const int* __restrict__ esrc, const int* __restrict__ edst,
    const int* __restrict__ row_start,
    const float* __restrict__ fa, const float* __restrict__ a_top,
    const float* __restrict__ sb, const ushort* __restrict__ emb,
    float* __restrict__ out)
{
    __shared__ ushort Bt[2][8192];     // 2 x 16 KB
    __shared__ float  sa_sh[16];
    const int t = threadIdx.x, lane = t & 63, wv = t >> 6;
    const int a0 = blockIdx.x * 16;

    // ---- sa for the block's 16 rows (16 threads per row, 16 elems each) ----
    {
        int r  = t >> 4;
        int cs = (t & 15) * 16;
        const float4* fr = (const float4*)(fa + (size_t)(a0 + r) * DD + cs);
        const float4* tv = (const float4*)(a_top + cs);
        float p = 0.f;
#pragma unroll
        for (int j = 0; j < 4; j++) {
            float4 x = fr[j], y = tv[j];
            p += x.x * y.x + x.y * y.y + x.z * y.z + x.w * y.w;
        }
        p += __shfl_xor(p, 1, 64); p += __shfl_xor(p, 2, 64);
        p += __shfl_xor(p, 4, 64); p += __shfl_xor(p, 8, 64);
        if ((t & 15) == 0) sa_sh[r] = p;
    }
    __syncthreads();
    const float sa_lane = sa_sh[lane & 15];   // lane holds sa[lane&15]

    const int beg  = row_start[a0], end = row_start[a0 + 16];
    const int nch  = (end - beg + 31) >> 5;
    const int el   = lane & 31;
    const int last = end - 1;

    f32x4 acc0 = {0,0,0,0}, acc1 = {0,0,0,0}, acc2 = {0,0,0,0},
          acc3 = {0,0,0,0}, racc = {0,0,0,0};

    const uint b0  = (uint)(uintptr_t)&Bt[0][0];          // LDS byte offset
    const uint trb = b0 + (uint)((lane >> 4) * 4096 + wv * 512 + (lane & 15) * 8);

    bf8 onesb;
    {
        short o = (lane & 15) == 0 ? (short)0x3F80 : (short)0;   // bf16 1.0 at n==0
#pragma unroll
        for (int j = 0; j < 8; j++) onesb[j] = o;
    }

#define STAGE(BQ, DREG)                                                        \
    {                                                                          \
        _Pragma("unroll")                                                      \
        for (int i_ = 0; i_ < 4; i_++) {                                       \
            int W_  = wv * 4 + i_;                                             \
            int k_  = ((W_ >> 1) << 2) | ((lane >> 1) & 3);                    \
            int dk_ = __shfl((DREG), k_, 64);                                  \
            const ushort* gs_ = emb + (size_t)dk_ * DD                         \
                + (W_ & 1) * 128 + ((lane >> 3) & 7) * 16 + (lane & 1) * 8;    \
            __builtin_amdgcn_global_load_lds(                                  \
                (const __attribute__((address_space(1))) void*)(uintptr_t)gs_, \
                (__attribute__((address_space(3))) void*)(uint)((BQ) + (uint)(W_ * 1024)), \
                16, 0, 0);                                                     \
        }                                                                      \
    }

    if (nch > 0) {
        int   i0   = min(beg + el, last);
        int   sr_c = esrc[i0] - a0;
        int   d0   = edst[i0];
        int   i1   = min(beg + 32 + el, last);
        int   d_n  = edst[i1];
        int   sr_n = esrc[i1] - a0;
        float sb_c = sb[d0];
        STAGE(b0, d0);                                   // chunk 0 -> buf 0

        for (int tc = 0; tc < nch; ++tc) {
            const int p = tc & 1;

            // ---- A-frag (16x32 scores) for chunk tc, in registers ----
            bool  val = (beg + tc * 32 + el) < end;
            float lg  = __shfl(sa_lane, sr_c, 64) + sb_c;
            float elu = lg > 0.f ? lg : 0.1f * (__expf(lg) - 1.f);
            float s   = val ? __expf(elu) : 0.f;
            uint pack = (uint)f2bf(s) | ((uint)sr_c << 16);
            bf8 af;
#pragma unroll
            for (int j = 0; j < 8; j++) {
                uint v = (uint)__shfl((int)pack, ((lane >> 4) << 3) + j, 64);
                af[j]  = (short)(((v >> 16) == (uint)(lane & 15))
                                     ? (ushort)(v & 0xFFFFu) : (ushort)0);
            }

            const bool more = (tc + 1) < nch;
            int d_nn = 0, sr_nn = 0; float sb_nn = 0.f;
            if (more) {
                sb_nn   = sb[d_n];
                int i2  = min(beg + (tc + 2) * 32 + el, last);
                d_nn    = edst[i2];
                sr_nn   = esrc[i2] - a0;
                uint bq = b0 + (uint)((p ^ 1) * 16384);
                STAGE(bq, d_n);                          // chunk tc+1 -> other buf
                asm volatile("s_waitcnt vmcnt(7)" ::: "memory");
            } else {
                asm volatile("s_waitcnt vmcnt(0)" ::: "memory");
            }
            __builtin_amdgcn_s_barrier();

            // ---- B-frags via hardware transpose reads of buf p ----
            const uint base = trb + (uint)(p * 16384);
            u32x2 t0, t1, t2, t3, t4, t5, t6, t7;
            asm volatile("ds_read_b64_tr_b16 %0, %1" : "=v"(t0) : "v"(base));
            asm volatile("ds_read_b64_tr_b16 %0, %1" : "=v"(t1) : "v"(base + 2048u));
            asm volatile("ds_read_b64_tr_b16 %0, %1" : "=v"(t2) : "v"(base + 128u));
            asm volatile("ds_read_b64_tr_b16 %0, %1" : "=v"(t3) : "v"(base + 2176u));
            asm volatile("ds_read_b64_tr_b16 %0, %1" : "=v"(t4) : "v"(base + 256u));
            asm volatile("ds_read_b64_tr_b16 %0, %1" : "=v"(t5) : "v"(base + 2304u));
            asm volatile("ds_read_b64_tr_b16 %0, %1" : "=v"(t6) : "v"(base + 384u));
            asm volatile("ds_read_b64_tr_b16 %0, %1" : "=v"(t7) : "v"(base + 2432u));
            asm volatile("s_waitcnt lgkmcnt(0)" ::: "memory");
            __builtin_amdgcn_sched_barrier(0);

            union { bf8 v; u32x2 h[2]; } U;
            bf8 bf0, bf1, bf2, bf3;
            U.h[0] = t0; U.h[1] = t1; bf0 = U.v;
            U.h[0] = t2; U.h[1] = t3; bf1 = U.v;
            U.h[0] = t4; U.h[1] = t5; bf2 = U.v;
            U.h[0] = t6; U.h[1] = t7; bf3 = U.v;

            acc0 = __builtin_amdgcn_mfma_f32_16x16x32_bf16(af, bf0, acc0, 0, 0, 0);
            acc1 = __builtin_amdgcn_mfma_f32_16x16x32_bf16(af, bf1, acc1, 0, 0, 0);
            acc2 = __builtin_amdgcn_mfma_f32_16x16x32_bf16(af, bf2, acc2, 0, 0, 0);
            acc3 = __builtin_amdgcn_mfma_f32_16x16x32_bf16(af, bf3, acc3, 0, 0, 0);
            racc = __builtin_amdgcn_mfma_f32_16x16x32_bf16(af, onesb, racc, 0, 0, 0);

            __builtin_amdgcn_s_barrier();

            sr_c = sr_n; sb_c = sb_nn; d_n = d_nn; sr_n = sr_nn;
        }
    }

    // ---- epilogue: out[row][col] = acc/rs ; D layout col=lane&15, row=(lane>>4)*4+reg ----
#pragma unroll
    for (int reg = 0; reg < 4; reg++) {
        float rsv = __shfl(racc[reg], lane & 48, 64);     // D[row][0] lives at lane&15==0
        float iv  = (rsv == 0.f) ? 0.f : (1.f / rsv);     // rs==0 => no edges => zeros
        int   row = a0 + (lane >> 4) * 4 + reg;
        float* op = out + (size_t)row * DD + wv * 64 + (lane & 15);
        op[0]  = acc0[reg] * iv;
        op[16] = acc1[reg] * iv;
        op[32] = acc2[reg] * iv;
        op[48] = acc3[reg] * iv;
    }
#undef STAGE
}

extern "C" void kernel_launch(void* const* d_in, const int* in_sizes, int n_in,
                              void* d_out, int out_size, void* d_ws, size_t ws_size,
                              hipStream_t stream)
{
    const float* fa   = (const float*)d_in[0];
    const float* fb   = (const float*)d_in[1];
    const float* W    = (const float*)d_in[2];
    const float* bias = (const float*)d_in[3];
    const float* avec = (const float*)d_in[4];
    const int*   esrc = (const int*)d_in[5];
    const int*   edst = (const int*)d_in[6];
    float*       out  = (float*)d_out;

    char*   ws        = (char*)d_ws;
    ushort* emb_b     = (ushort*)ws;                               // 25.6 MB
    float*  s_b       = (float*)(ws + (size_t)NB_N * DD * 2);      // NB
    int*    row_start = (int*)(s_b + NB_N);                        // NA+1
    ushort* Wt        = (ushort*)(row_start + NA_N + 2);           // 128 KB

    prep_k   <<<16 + (NE_N + 255) / 256, 256, 0, stream>>>(W, Wt, esrc, row_start);
    gemm_mfma<<<(NB_N + 63) / 64, 256, 0, stream>>>(fb, Wt, bias, avec + DD,
                                                    emb_b, s_b);
    edge_mfma<<<NA_N / 16, 256, 0, stream>>>(esrc, edst, row_start, fa, avec,
                                             s_b, emb_b, out);
}

// Round 10
// 111.812 us; speedup vs baseline: 1.0161x; 1.0161x over previous
//
#include <hip/hip_runtime.h>
#include <cstdint>

#define NA_N 50000
#define NB_N 50000
#define NE_N 800000
#define DD 256
#define GEMM_NBLK 782            // (NB_N+63)/64

using bf8   = __attribute__((ext_vector_type(8))) short;   // 8 bf16 = 4 VGPR
using f32x4 = __attribute__((ext_vector_type(4))) float;
using u16x8 = __attribute__((ext_vector_type(8))) ushort;

__device__ __forceinline__ ushort f2bf(float f) {
    uint u = __float_as_uint(f);
    uint r = (u + 0x7fffu + ((u >> 16) & 1u)) >> 16;       // RNE
    return (ushort)r;
}
__device__ __forceinline__ float bf2f(ushort u) {
    return __uint_as_float(((uint)u) << 16);
}

// ------- prep: transpose+cast W -> Wt[n][k] (bf16), 16 blocks -------
__global__ __launch_bounds__(256) void prep_k(const float* __restrict__ W,
                                              ushort* __restrict__ Wt)
{
    __shared__ float T[64][65];
    const int bi = blockIdx.x & 3;        // k tile
    const int bj = blockIdx.x >> 2;       // n tile
    const int lane = threadIdx.x & 63, w = threadIdx.x >> 6;
    for (int i = w; i < 64; i += 4)
        T[i][lane] = W[(size_t)(bi * 64 + i) * DD + bj * 64 + lane];
    __syncthreads();
    for (int i = w; i < 64; i += 4)
        Wt[(size_t)(bj * 64 + i) * DD + bi * 64 + lane] = f2bf(T[lane][i]);
}

// ------- GEMM: emb_b = bf16(fb)@W + bias ; fused s_b = emb@a_bot ; tail blocks build row_start -------
__global__ __launch_bounds__(256) void gemm_mfma(
    const float* __restrict__ A, const ushort* __restrict__ Wt,
    const float* __restrict__ bias, const float* __restrict__ a_bot,
    ushort* __restrict__ C, float* __restrict__ s_b,
    const int* __restrict__ esrc, int* __restrict__ row_start)
{
    __shared__ ushort As[64 * 264];
    __shared__ float  sdot[4][64];

    if (blockIdx.x >= GEMM_NBLK) {        // row_start builder (independent work)
        int e = (blockIdx.x - GEMM_NBLK) * 256 + threadIdx.x;
        if (e >= NE_N) return;
        int s    = esrc[e];
        int prev = (e == 0) ? -1 : esrc[e - 1];
        for (int r = prev + 1; r <= s; r++) row_start[r] = e;
        if (e == NE_N - 1)
            for (int r = s + 1; r <= NA_N; r++) row_start[r] = NE_N;
        return;
    }

    const int t  = threadIdx.x;
    const int r0 = blockIdx.x * 64;

#pragma unroll
    for (int i = 0; i < 16; i++) {
        int flat = i * 256 + t;
        int row  = flat >> 6;
        int c4   = flat & 63;
        int gr   = r0 + row; if (gr >= NB_N) gr = 0;      // clamp tail
        f32x4 v = __builtin_nontemporal_load(
                      ((const f32x4*)(A + (size_t)gr * DD)) + c4);
        ushort4 b;
        b.x = f2bf(v[0]); b.y = f2bf(v[1]); b.z = f2bf(v[2]); b.w = f2bf(v[3]);
        *(ushort4*)&As[row * 264 + c4 * 4] = b;
    }
    __syncthreads();

    const int lane = t & 63;
    const int wv   = t >> 6;
    const int lr   = lane & 15;
    const int lk   = (lane >> 4) * 8;

    f32x4 acc[4][4];
#pragma unroll
    for (int m = 0; m < 4; m++)
#pragma unroll
        for (int n = 0; n < 4; n++) acc[m][n] = (f32x4){0.f, 0.f, 0.f, 0.f};

#pragma unroll
    for (int ks = 0; ks < 8; ks++) {
        const int k0 = ks * 32;
        bf8 af[4], bb[4];
#pragma unroll
        for (int m = 0; m < 4; m++)
            af[m] = *(const bf8*)&As[(m * 16 + lr) * 264 + k0 + lk];
#pragma unroll
        for (int n = 0; n < 4; n++) {
            int col = wv * 64 + n * 16 + lr;
            bb[n] = *(const bf8*)&Wt[(size_t)col * DD + k0 + lk];
        }
#pragma unroll
        for (int m = 0; m < 4; m++)
#pragma unroll
            for (int n = 0; n < 4; n++)
                acc[m][n] = __builtin_amdgcn_mfma_f32_16x16x32_bf16(
                    af[m], bb[n], acc[m][n], 0, 0, 0);
    }

    float abv[4];
#pragma unroll
    for (int n = 0; n < 4; n++) abv[n] = a_bot[wv * 64 + n * 16 + lr];

    float part[4][4];
#pragma unroll
    for (int m = 0; m < 4; m++)
#pragma unroll
        for (int r = 0; r < 4; r++) part[m][r] = 0.f;

#pragma unroll
    for (int m = 0; m < 4; m++)
#pragma unroll
        for (int n = 0; n < 4; n++) {
            int   col = wv * 64 + n * 16 + lr;
            float bv  = bias[col];
#pragma unroll
            for (int r = 0; r < 4; r++) {
                int   rowg = r0 + m * 16 + (lane >> 4) * 4 + r;  // C: col=lane&15, row=(lane>>4)*4+r
                float v    = acc[m][n][r] + bv;
                if (rowg < NB_N) C[(size_t)rowg * DD + col] = f2bf(v);
                part[m][r] = fmaf(v, abv[n], part[m][r]);
            }
        }

#pragma unroll
    for (int m = 0; m < 4; m++)
#pragma unroll
        for (int r = 0; r < 4; r++) {
#pragma unroll
            for (int off = 1; off < 16; off <<= 1)
                part[m][r] += __shfl_xor(part[m][r], off, 64);
        }
    if (lr == 0) {
#pragma unroll
        for (int m = 0; m < 4; m++)
#pragma unroll
            for (int r = 0; r < 4; r++)
                sdot[wv][m * 16 + (lane >> 4) * 4 + r] = part[m][r];
    }
    __syncthreads();
    if (t < 64) {
        int rowg = r0 + t;
        if (rowg < NB_N)
            s_b[rowg] = sdot[0][t] + sdot[1][t] + sdot[2][t] + sdot[3][t];
    }
}

// -------- edge aggregation: wave/row, quarter-wave/edge, depth-2 pipeline, NT hints --------
// fa/edst streamed once -> nontemporal loads (don't evict the gather table from L2);
// out written once -> nontemporal store. emb/sb stay cached.
__global__ __launch_bounds__(256) void edge_agg7(
    const int* __restrict__ edst, const int* __restrict__ row_start,
    const float* __restrict__ fa, const float* __restrict__ a_top,
    const float* __restrict__ sb, const ushort* __restrict__ emb,
    float* __restrict__ out)
{
    const int lane = threadIdx.x & 63;
    const int a    = blockIdx.x * 4 + (threadIdx.x >> 6);
    if (a >= NA_N) return;

    // fused s_a: dot(fa[a,:], a_top) — fa streamed once, NT
    f32x4 av = __builtin_nontemporal_load(((const f32x4*)(fa + (size_t)a * DD)) + lane);
    f32x4 tv = *(((const f32x4*)a_top) + lane);
    float sa_a = av[0] * tv[0] + av[1] * tv[1] + av[2] * tv[2] + av[3] * tv[3];
#pragma unroll
    for (int off = 1; off < 64; off <<= 1) sa_a += __shfl_xor(sa_a, off, 64);

    const int g = lane >> 4;          // quarter-wave group: one edge per stage
    const int c = lane & 15;          // 16-col block within row
    const int beg = row_start[a], end = row_start[a + 1];

    float accA[8], accB[8];
#pragma unroll
    for (int j = 0; j < 8; j++) { accA[j] = 0.f; accB[j] = 0.f; }
    float rs = 0.f;

    if (beg < end) {
        const int last = end - 1;

        int   pc  = beg + g;                      // current-stage position
        int   pn  = pc + 4;                       // next-stage position
        int   dc  = __builtin_nontemporal_load(edst + min(pc, last));
        int   dn  = __builtin_nontemporal_load(edst + min(pn, last));
        float sbc = sb[dc];
        float sbn = sb[dn];
        const ushort* rc = emb + (size_t)dc * DD + c * 16;
        u16x8 ua = *(const u16x8*)rc;             // stage-0 gathers in flight
        u16x8 ub = *(const u16x8*)(rc + 8);

#pragma unroll 2
        for (int e = beg; e < end; e += 4) {
            // issue next-stage gathers (independent of current consumption)
            const ushort* rn = emb + (size_t)dn * DD + c * 16;
            u16x8 na = *(const u16x8*)rn;
            u16x8 nb = *(const u16x8*)(rn + 8);
            // preload stage+2 index & sb
            int   p2  = pn + 4;
            int   d2  = __builtin_nontemporal_load(edst + min(p2, last));
            float sb2 = sb[d2];

            // score for current stage
            float lg = sa_a + sbc;
            float el = lg > 0.f ? lg : 0.1f * (__expf(lg) - 1.f);
            float s  = (pc < end) ? __expf(el) : 0.f;

            // consume current gathers (waits only on ua/ub — older loads)
#pragma unroll
            for (int j = 0; j < 8; j++) {
                accA[j] = fmaf(s, bf2f(ua[j]), accA[j]);
                accB[j] = fmaf(s, bf2f(ub[j]), accB[j]);
            }
            rs += s;

            // rotate pipeline (pure renaming after unroll)
            pc = pn;  dc = dn;  sbc = sbn;
            ua = na;  ub = nb;
            pn = p2;  dn = d2;  sbn = sb2;
        }
    }

    // combine the 4 quarter-wave partials (xor over group bits 16,32)
#pragma unroll
    for (int j = 0; j < 8; j++) {
        accA[j] += __shfl_xor(accA[j], 16, 64);
        accA[j] += __shfl_xor(accA[j], 32, 64);
        accB[j] += __shfl_xor(accB[j], 16, 64);
        accB[j] += __shfl_xor(accB[j], 32, 64);
    }
    rs += __shfl_xor(rs, 16, 64);
    rs += __shfl_xor(rs, 32, 64);

    if (g == 0) {                      // lanes 0-15 write cols c*16..c*16+15
        const float inv = (rs == 0.f) ? 1.f : (1.f / rs);
        float* op = out + (size_t)a * DD + c * 16;
        f32x4 o0 = { accA[0] * inv, accA[1] * inv, accA[2] * inv, accA[3] * inv };
        f32x4 o1 = { accA[4] * inv, accA[5] * inv, accA[6] * inv, accA[7] * inv };
        f32x4 o2 = { accB[0] * inv, accB[1] * inv, accB[2] * inv, accB[3] * inv };
        f32x4 o3 = { accB[4] * inv, accB[5] * inv, accB[6] * inv, accB[7] * inv };
        __builtin_nontemporal_store(o0, (f32x4*)(op + 0));
        __builtin_nontemporal_store(o1, (f32x4*)(op + 4));
        __builtin_nontemporal_store(o2, (f32x4*)(op + 8));
        __builtin_nontemporal_store(o3, (f32x4*)(op + 12));
    }
}

extern "C" void kernel_launch(void* const* d_in, const int* in_sizes, int n_in,
                              void* d_out, int out_size, void* d_ws, size_t ws_size,
                              hipStream_t stream)
{
    const float* fa   = (const float*)d_in[0];
    const float* fb   = (const float*)d_in[1];
    const float* W    = (const float*)d_in[2];
    const float* bias = (const float*)d_in[3];
    const float* avec = (const float*)d_in[4];
    const int*   esrc = (const int*)d_in[5];
    const int*   edst = (const int*)d_in[6];
    float*       out  = (float*)d_out;

    char*   ws        = (char*)d_ws;
    ushort* emb_b     = (ushort*)ws;                               // 25.6 MB
    float*  s_b       = (float*)(ws + (size_t)NB_N * DD * 2);      // NB
    int*    row_start = (int*)(s_b + NB_N);                        // NA+1
    ushort* Wt        = (ushort*)(row_start + NA_N + 2);           // 128 KB

    prep_k   <<<16, 256, 0, stream>>>(W, Wt);
    gemm_mfma<<<GEMM_NBLK + (NE_N + 255) / 256, 256, 0, stream>>>(
        fb, Wt, bias, avec + DD, emb_b, s_b, esrc, row_start);
    edge_agg7<<<(NA_N + 3) / 4, 256, 0, stream>>>(edst, row_start, fa, avec,
                                                  s_b, emb_b, out);
}

// Round 11
// 106.502 us; speedup vs baseline: 1.0667x; 1.0499x over previous
//
#include <hip/hip_runtime.h>
#include <cstdint>

#define NA_N 50000
#define NB_N 50000
#define NE_N 800000
#define DD 256
#define GEMM_NBLK 782            // (NB_N+63)/64

using bf8   = __attribute__((ext_vector_type(8))) short;   // 8 bf16 = 4 VGPR
using f32x4 = __attribute__((ext_vector_type(4))) float;
using u16x8 = __attribute__((ext_vector_type(8))) ushort;

__device__ __forceinline__ ushort f2bf(float f) {
    uint u = __float_as_uint(f);
    uint r = (u + 0x7fffu + ((u >> 16) & 1u)) >> 16;       // RNE
    return (ushort)r;
}
__device__ __forceinline__ float bf2f(ushort u) {
    return __uint_as_float(((uint)u) << 16);
}

// ------- prep: transpose+cast W -> Wt[n][k] (bf16), 16 blocks -------
__global__ __launch_bounds__(256) void prep_k(const float* __restrict__ W,
                                              ushort* __restrict__ Wt)
{
    __shared__ float T[64][65];
    const int bi = blockIdx.x & 3;        // k tile
    const int bj = blockIdx.x >> 2;       // n tile
    const int lane = threadIdx.x & 63, w = threadIdx.x >> 6;
    for (int i = w; i < 64; i += 4)
        T[i][lane] = W[(size_t)(bi * 64 + i) * DD + bj * 64 + lane];
    __syncthreads();
    for (int i = w; i < 64; i += 4)
        Wt[(size_t)(bj * 64 + i) * DD + bi * 64 + lane] = f2bf(T[lane][i]);
}

// ------- GEMM: emb_b = bf16(fb)@W + bias ; fused s_b = emb@a_bot ; tail blocks build row_start -------
// ks-loop software-pipelines the 4 global B-frag loads one step ahead so their
// ~200cy L2 latency hides under the 16-MFMA cluster of the previous step.
__global__ __launch_bounds__(256) void gemm_mfma(
    const float* __restrict__ A, const ushort* __restrict__ Wt,
    const float* __restrict__ bias, const float* __restrict__ a_bot,
    ushort* __restrict__ C, float* __restrict__ s_b,
    const int* __restrict__ esrc, int* __restrict__ row_start)
{
    __shared__ ushort As[64 * 264];
    __shared__ float  sdot[4][64];

    if (blockIdx.x >= GEMM_NBLK) {        // row_start builder (independent work)
        int e = (blockIdx.x - GEMM_NBLK) * 256 + threadIdx.x;
        if (e >= NE_N) return;
        int s    = esrc[e];
        int prev = (e == 0) ? -1 : esrc[e - 1];
        for (int r = prev + 1; r <= s; r++) row_start[r] = e;
        if (e == NE_N - 1)
            for (int r = s + 1; r <= NA_N; r++) row_start[r] = NE_N;
        return;
    }

    const int t  = threadIdx.x;
    const int r0 = blockIdx.x * 64;

#pragma unroll
    for (int i = 0; i < 16; i++) {
        int flat = i * 256 + t;
        int row  = flat >> 6;
        int c4   = flat & 63;
        int gr   = r0 + row; if (gr >= NB_N) gr = 0;      // clamp tail
        float4 v = ((const float4*)(A + (size_t)gr * DD))[c4];
        ushort4 b;
        b.x = f2bf(v.x); b.y = f2bf(v.y); b.z = f2bf(v.z); b.w = f2bf(v.w);
        *(ushort4*)&As[row * 264 + c4 * 4] = b;
    }
    __syncthreads();

    const int lane = t & 63;
    const int wv   = t >> 6;
    const int lr   = lane & 15;
    const int lk   = (lane >> 4) * 8;
    const ushort* Wb = Wt + (size_t)(wv * 64 + lr) * DD + lk;   // base for this lane's cols

    f32x4 acc[4][4];
#pragma unroll
    for (int m = 0; m < 4; m++)
#pragma unroll
        for (int n = 0; n < 4; n++) acc[m][n] = (f32x4){0.f, 0.f, 0.f, 0.f};

    bf8 bbc[4], bbn[4];
#pragma unroll
    for (int n = 0; n < 4; n++)                       // preload ks=0 B-frags
        bbc[n] = *(const bf8*)(Wb + (size_t)n * 16 * DD);

#pragma unroll
    for (int ks = 0; ks < 8; ks++) {
        const int k0 = ks * 32;
        if (ks < 7) {
#pragma unroll
            for (int n = 0; n < 4; n++)               // prefetch ks+1 B-frags
                bbn[n] = *(const bf8*)(Wb + (size_t)n * 16 * DD + k0 + 32);
        }
        bf8 af[4];
#pragma unroll
        for (int m = 0; m < 4; m++)
            af[m] = *(const bf8*)&As[(m * 16 + lr) * 264 + k0 + lk];
#pragma unroll
        for (int m = 0; m < 4; m++)
#pragma unroll
            for (int n = 0; n < 4; n++)
                acc[m][n] = __builtin_amdgcn_mfma_f32_16x16x32_bf16(
                    af[m], bbc[n], acc[m][n], 0, 0, 0);
#pragma unroll
        for (int n = 0; n < 4; n++) bbc[n] = bbn[n];  // static rotation
    }

    float abv[4];
#pragma unroll
    for (int n = 0; n < 4; n++) abv[n] = a_bot[wv * 64 + n * 16 + lr];

    float part[4][4];
#pragma unroll
    for (int m = 0; m < 4; m++)
#pragma unroll
        for (int r = 0; r < 4; r++) part[m][r] = 0.f;

#pragma unroll
    for (int m = 0; m < 4; m++)
#pragma unroll
        for (int n = 0; n < 4; n++) {
            int   col = wv * 64 + n * 16 + lr;
            float bv  = bias[col];
#pragma unroll
            for (int r = 0; r < 4; r++) {
                int   rowg = r0 + m * 16 + (lane >> 4) * 4 + r;  // C: col=lane&15, row=(lane>>4)*4+r
                float v    = acc[m][n][r] + bv;
                if (rowg < NB_N) C[(size_t)rowg * DD + col] = f2bf(v);
                part[m][r] = fmaf(v, abv[n], part[m][r]);
            }
        }

#pragma unroll
    for (int m = 0; m < 4; m++)
#pragma unroll
        for (int r = 0; r < 4; r++) {
#pragma unroll
            for (int off = 1; off < 16; off <<= 1)
                part[m][r] += __shfl_xor(part[m][r], off, 64);
        }
    if (lr == 0) {
#pragma unroll
        for (int m = 0; m < 4; m++)
#pragma unroll
            for (int r = 0; r < 4; r++)
                sdot[wv][m * 16 + (lane >> 4) * 4 + r] = part[m][r];
    }
    __syncthreads();
    if (t < 64) {
        int rowg = r0 + t;
        if (rowg < NB_N)
            s_b[rowg] = sdot[0][t] + sdot[1][t] + sdot[2][t] + sdot[3][t];
    }
}

// -------- edge aggregation: wave/row, quarter-wave/edge, depth-2 software pipeline --------
__global__ __launch_bounds__(256) void edge_agg7(
    const int* __restrict__ edst, const int* __restrict__ row_start,
    const float* __restrict__ fa, const float* __restrict__ a_top,
    const float* __restrict__ sb, const ushort* __restrict__ emb,
    float* __restrict__ out)
{
    const int lane = threadIdx.x & 63;
    const int a    = blockIdx.x * 4 + (threadIdx.x >> 6);
    if (a >= NA_N) return;

    // fused s_a: dot(fa[a,:], a_top)
    float4 av = ((const float4*)(fa + (size_t)a * DD))[lane];
    float4 tv = ((const float4*)a_top)[lane];
    float  sa_a = av.x * tv.x + av.y * tv.y + av.z * tv.z + av.w * tv.w;
#pragma unroll
    for (int off = 1; off < 64; off <<= 1) sa_a += __shfl_xor(sa_a, off, 64);

    const int g = lane >> 4;          // quarter-wave group: one edge per stage
    const int c = lane & 15;          // 16-col block within row
    const int beg = row_start[a], end = row_start[a + 1];

    float accA[8], accB[8];
#pragma unroll
    for (int j = 0; j < 8; j++) { accA[j] = 0.f; accB[j] = 0.f; }
    float rs = 0.f;

    if (beg < end) {
        const int last = end - 1;

        int   pc  = beg + g;                      // current-stage position
        int   pn  = pc + 4;                       // next-stage position
        int   dc  = edst[min(pc, last)];
        int   dn  = edst[min(pn, last)];
        float sbc = sb[dc];
        float sbn = sb[dn];
        const ushort* rc = emb + (size_t)dc * DD + c * 16;
        u16x8 ua = *(const u16x8*)rc;             // stage-0 gathers in flight
        u16x8 ub = *(const u16x8*)(rc + 8);

#pragma unroll 2
        for (int e = beg; e < end; e += 4) {
            // issue next-stage gathers (independent of current consumption)
            const ushort* rn = emb + (size_t)dn * DD + c * 16;
            u16x8 na = *(const u16x8*)rn;
            u16x8 nb = *(const u16x8*)(rn + 8);
            // preload stage+2 index & sb
            int   p2  = pn + 4;
            int   d2  = edst[min(p2, last)];
            float sb2 = sb[d2];

            // score for current stage
            float lg = sa_a + sbc;
            float el = lg > 0.f ? lg : 0.1f * (__expf(lg) - 1.f);
            float s  = (pc < end) ? __expf(el) : 0.f;

            // consume current gathers (waits only on ua/ub — older loads)
#pragma unroll
            for (int j = 0; j < 8; j++) {
                accA[j] = fmaf(s, bf2f(ua[j]), accA[j]);
                accB[j] = fmaf(s, bf2f(ub[j]), accB[j]);
            }
            rs += s;

            // rotate pipeline (pure renaming after unroll)
            pc = pn;  dc = dn;  sbc = sbn;
            ua = na;  ub = nb;
            pn = p2;  dn = d2;  sbn = sb2;
        }
    }

    // combine the 4 quarter-wave partials (xor over group bits 16,32)
#pragma unroll
    for (int j = 0; j < 8; j++) {
        accA[j] += __shfl_xor(accA[j], 16, 64);
        accA[j] += __shfl_xor(accA[j], 32, 64);
        accB[j] += __shfl_xor(accB[j], 16, 64);
        accB[j] += __shfl_xor(accB[j], 32, 64);
    }
    rs += __shfl_xor(rs, 16, 64);
    rs += __shfl_xor(rs, 32, 64);

    if (g == 0) {                      // lanes 0-15 write cols c*16..c*16+15
        const float inv = (rs == 0.f) ? 1.f : (1.f / rs);
        float* op = out + (size_t)a * DD + c * 16;
        float4 o0 = { accA[0] * inv, accA[1] * inv, accA[2] * inv, accA[3] * inv };
        float4 o1 = { accA[4] * inv, accA[5] * inv, accA[6] * inv, accA[7] * inv };
        float4 o2 = { accB[0] * inv, accB[1] * inv, accB[2] * inv, accB[3] * inv };
        float4 o3 = { accB[4] * inv, accB[5] * inv, accB[6] * inv, accB[7] * inv };
        *(float4*)(op + 0)  = o0;
        *(float4*)(op + 4)  = o1;
        *(float4*)(op + 8)  = o2;
        *(float4*)(op + 12) = o3;
    }
}

extern "C" void kernel_launch(void* const* d_in, const int* in_sizes, int n_in,
                              void* d_out, int out_size, void* d_ws, size_t ws_size,
                              hipStream_t stream)
{
    const float* fa   = (const float*)d_in[0];
    const float* fb   = (const float*)d_in[1];
    const float* W    = (const float*)d_in[2];
    const float* bias = (const float*)d_in[3];
    const float* avec = (const float*)d_in[4];
    const int*   esrc = (const int*)d_in[5];
    const int*   edst = (const int*)d_in[6];
    float*       out  = (float*)d_out;

    char*   ws        = (char*)d_ws;
    ushort* emb_b     = (ushort*)ws;                               // 25.6 MB
    float*  s_b       = (float*)(ws + (size_t)NB_N * DD * 2);      // NB
    int*    row_start = (int*)(s_b + NB_N);                        // NA+1
    ushort* Wt        = (ushort*)(row_start + NA_N + 2);           // 128 KB

    prep_k   <<<16, 256, 0, stream>>>(W, Wt);
    gemm_mfma<<<GEMM_NBLK + (NE_N + 255) / 256, 256, 0, stream>>>(
        fb, Wt, bias, avec + DD, emb_b, s_b, esrc, row_start);
    edge_agg7<<<(NA_N + 3) / 4, 256, 0, stream>>>(edst, row_start, fa, avec,
                                                  s_b, emb_b, out);
}